// Round 6
// baseline (79.239 us; speedup 1.0000x reference)
//
#include <hip/hip_runtime.h>
#include <hip/hip_bf16.h>

typedef __attribute__((ext_vector_type(4))) short short4v;
typedef __attribute__((ext_vector_type(4))) float float4v;

#define NHEADS 4
#define DMODEL 64
#define EPSV 1e-5f
#define QSCALE 0.36067376022224085f   // log2(e) / sqrt(16)

__device__ inline short bf16rn(float f) {
    __hip_bfloat16 h = __float2bfloat16(f);
    return __builtin_bit_cast(short, h);
}

__device__ inline float exp2fast(float x) { return __builtin_amdgcn_exp2f(x); }

// ---------- merged projections (unchanged from R5) ----------
__global__ __launch_bounds__(256)
void proj_all_k(const float* __restrict__ Wk, const float* __restrict__ bk,
                const float* __restrict__ Wv, const float* __restrict__ bv,
                const float* __restrict__ Wq, const float* __restrict__ bq,
                const float* __restrict__ fkey, const float* __restrict__ fpix,
                short4v* __restrict__ kfrag, short4v* __restrict__ vfrag,
                short4v* __restrict__ qfrag, int M, int N) {
    __shared__ float xs[64][64];
    __shared__ float wsm[64][65];
    const int t = threadIdx.x;
    const int kvblocks = M >> 6;
    const bool isKV = (int)blockIdx.x < kvblocks;
    const int c0 = (isKV ? blockIdx.x : blockIdx.x - kvblocks) * 64;
    const float* x = isKV ? fkey : fpix;
    const int NC = isKV ? M : N;

    for (int i = t; i < 64 * 64; i += 256) {
        xs[i >> 6][i & 63] = x[(size_t)(i >> 6) * NC + c0 + (i & 63)];
        if (isKV) wsm[i >> 6][i & 63] = Wv[i];
    }
    __syncthreads();
    const int CT = NC >> 4;

    {
        const float* W = isKV ? Wk : Wq;
        const float* b = isKV ? bk : bq;
        const float scale = isKV ? 1.f : QSCALE;
        short4v* outf = isKV ? kfrag : qfrag;
        const int mm = t & 63;
        const int qd = __builtin_amdgcn_readfirstlane(t >> 6);
        const int m = c0 + mm;
        float acc[16];
        #pragma unroll
        for (int cc = 0; cc < 16; ++cc) acc[cc] = b[qd * 16 + cc];
        #pragma unroll 8
        for (int d = 0; d < 64; ++d) {
            float xv = xs[d][mm];
            #pragma unroll
            for (int cc = 0; cc < 16; ++cc)
                acc[cc] = fmaf(W[(qd * 16 + cc) * 64 + d], xv, acc[cc]);
        }
        #pragma unroll
        for (int h = 0; h < 4; ++h) {
            short4v pk;
            #pragma unroll
            for (int j = 0; j < 4; ++j) pk[j] = bf16rn(acc[j * 4 + h] * scale);
            outf[((size_t)(h * CT + (m >> 4))) * 64 + (m & 15) + 16 * qd] = pk;
        }
    }
    if (isKV) {
        const int lane = t & 63;
        const int w = t >> 6;
        const int d = lane >> 2, h = lane & 3;
        const float b0 = bv[lane];
        #pragma unroll
        for (int r = 0; r < 4; ++r) {
            const int mg = r * 4 + w;
            float a0 = b0, a1 = b0, a2 = b0, a3 = b0;
            #pragma unroll 8
            for (int dd = 0; dd < 64; ++dd) {
                float wv = wsm[lane][dd];
                float4 xv = *(const float4*)&xs[dd][mg * 4];
                a0 = fmaf(wv, xv.x, a0); a1 = fmaf(wv, xv.y, a1);
                a2 = fmaf(wv, xv.z, a2); a3 = fmaf(wv, xv.w, a3);
            }
            short4v pk;
            pk[0] = bf16rn(a0); pk[1] = bf16rn(a1); pk[2] = bf16rn(a2); pk[3] = bf16rn(a3);
            const int m0 = c0 + mg * 4;
            vfrag[((size_t)(h * CT + (m0 >> 4))) * 64 + d + 16 * ((m0 >> 2) & 3)] = pk;
        }
    }
}

// ---------- MFMA flash attention (unchanged from R5) ----------
__global__ __launch_bounds__(256)
void attn_mfma_k(const short4v* __restrict__ qf, const short4v* __restrict__ kf,
                 const short4v* __restrict__ vf, float* __restrict__ xatt,
                 int N, int M) {
    const int lane = threadIdx.x & 63;
    const int ck = threadIdx.x >> 6;
    const int nt = blockIdx.x;
    const int h = blockIdx.y;
    const int NT = N >> 4, MT = M >> 4;
    const int mtN = MT >> 2;
    const int mt0 = ck * mtN;

    const short4v q4 = qf[((size_t)(h * NT + nt)) * 64 + lane];
    const float4v zero4 = {0.f, 0.f, 0.f, 0.f};
    float4v O = zero4;
    float ld = 0.f;
    const int g4 = (lane >> 4) << 2;

    const short4v* kp = kf + ((size_t)(h * MT + mt0)) * 64 + lane;
    const short4v* vp = vf + ((size_t)(h * MT + mt0)) * 64 + lane;
    for (int it = 0; it < mtN; it += 4) {
        short4v ka[4], va[4];
        #pragma unroll
        for (int u = 0; u < 4; ++u) {
            ka[u] = kp[(it + u) * 64];
            va[u] = vp[(it + u) * 64];
        }
        #pragma unroll
        for (int u = 0; u < 4; ++u) {
            float4v s = __builtin_amdgcn_mfma_f32_16x16x16bf16_1k(ka[u], q4, zero4, 0, 0, 0);
            float p0 = exp2fast(s[0]), p1 = exp2fast(s[1]),
                  p2 = exp2fast(s[2]), p3 = exp2fast(s[3]);
            ld += (p0 + p1) + (p2 + p3);
            short4v pa;
            pa[0] = bf16rn(p0); pa[1] = bf16rn(p1); pa[2] = bf16rn(p2); pa[3] = bf16rn(p3);
            O = __builtin_amdgcn_mfma_f32_16x16x16bf16_1k(pa, va[u], O, 0, 0, 0);
        }
    }
    ld += __shfl_xor(ld, 16);
    ld += __shfl_xor(ld, 32);

    __shared__ float Osm[4][256];
    __shared__ float lsm[4][16];
    #pragma unroll
    for (int b = 0; b < 4; ++b)
        Osm[ck][(g4 + b) * 16 + (lane & 15)] = O[b];
    if (lane < 16) lsm[ck][lane] = ld;
    __syncthreads();

    const int t = threadIdx.x;
    const int d = t >> 4, q = t & 15;
    const float L = (lsm[0][q] + lsm[1][q]) + (lsm[2][q] + lsm[3][q]);
    const int oi = q * 16 + d;
    const float val = (Osm[0][oi] + Osm[1][oi]) + (Osm[2][oi] + Osm[3][oi]);
    xatt[(size_t)(d * NHEADS + h) * N + nt * 16 + q] = val / L;
}

// ---------- conv(Wm) + residual add + LN1 partials ----------
// grid (N/64, 4), 256 thr. Writes resid = fpix + Wm*xatt + bm and per-(channel,block)
// partial sum/sumsq over this block's 64 columns.
__global__ __launch_bounds__(256)
void conv_wm_resid_k(const float* __restrict__ W, const float* __restrict__ bias,
                     const float* __restrict__ xatt, const float* __restrict__ fpix,
                     float* __restrict__ resid, float* __restrict__ pb_s,
                     float* __restrict__ pb_q, int N) {
    __shared__ float xs[64][64];
    const int tid = threadIdx.x;
    const int bx = blockIdx.x;
    const int n0 = bx * 64;
    for (int i = tid; i < 64 * 64; i += 256) {
        int d = i >> 6, nn = i & 63;
        xs[d][nn] = xatt[(size_t)d * N + n0 + nn];
    }
    __syncthreads();
    const int nn = tid & 63;
    const int og = __builtin_amdgcn_readfirstlane((int)(tid >> 6));
    const int ow = blockIdx.y * 16 + og * 4;
    float acc[4];
    #pragma unroll
    for (int i = 0; i < 4; ++i) acc[i] = bias[ow + i];
    #pragma unroll 8
    for (int d = 0; d < 64; ++d) {
        float xv = xs[d][nn];
        #pragma unroll
        for (int i = 0; i < 4; ++i)
            acc[i] = fmaf(W[(ow + i) * 64 + d], xv, acc[i]);
    }
    #pragma unroll
    for (int i = 0; i < 4; ++i) {
        float r = acc[i] + fpix[(size_t)(ow + i) * N + n0 + nn];
        resid[(size_t)(ow + i) * N + n0 + nn] = r;
        float s = r, q = r * r;
        #pragma unroll
        for (int m = 1; m < 64; m <<= 1) {
            s += __shfl_xor(s, m);
            q += __shfl_xor(q, m);
        }
        if (nn == 0) {
            pb_s[(ow + i) * (N >> 6) + bx] = s;
            pb_q[(ow + i) * (N >> 6) + bx] = q;
        }
    }
}

// ---------- LN1 finalize + normalize + MLP(64->128->64) + add + LN2 partials ----------
// grid N/64, 512 thr. Reads resid + pb1 partials; writes t = fea + mlp(fea) and pb2.
__global__ __launch_bounds__(512)
void mlp_fused_k(const float* __restrict__ W1, const float* __restrict__ b1,
                 const float* __restrict__ W2, const float* __restrict__ b2,
                 const float* __restrict__ resid, const float* __restrict__ pb1s,
                 const float* __restrict__ pb1q, float* __restrict__ tbuf,
                 float* __restrict__ pb2s, float* __restrict__ pb2q, int N) {
    __shared__ float xs[64][65];
    __shared__ float hs[128][65];
    __shared__ float redS[8][64], redQ[8][64];
    __shared__ float lnA[64], lnB[64];
    const int tid = threadIdx.x;
    const int nb = N >> 6;                 // 80 partial blocks
    const int bx = blockIdx.x;
    const int n0 = bx * 64;

    // LN1 stats: redundant per-block reduce of [64][nb] partials
    {
        const int c = tid & 63, part = tid >> 6;     // 8 parts
        const int per = nb >> 3;                     // 10
        float s = 0.f, q = 0.f;
        for (int i = 0; i < per; ++i) {
            int b = part * per + i;
            s += pb1s[c * nb + b];
            q += pb1q[c * nb + b];
        }
        redS[part][c] = s; redQ[part][c] = q;
    }
    __syncthreads();
    if (tid < 64) {
        float s = 0.f, q = 0.f;
        #pragma unroll
        for (int p = 0; p < 8; ++p) { s += redS[p][tid]; q += redQ[p][tid]; }
        float mean = s / (float)N;
        float var = q / (float)N - mean * mean;
        float rstd = rsqrtf(var + EPSV);
        lnA[tid] = rstd;
        lnB[tid] = -mean * rstd;
    }
    __syncthreads();

    // normalize resid tile -> xs (this is fea)
    for (int i = tid; i < 64 * 64; i += 512) {
        int c = i >> 6, nn = i & 63;
        xs[c][nn] = resid[(size_t)c * N + n0 + nn] * lnA[c] + lnB[c];
    }
    __syncthreads();

    const int col = tid & 63;
    const int w = __builtin_amdgcn_readfirstlane((int)(tid >> 6));  // 0..7

    // conv1: 128 outputs, wave w handles h = w*16 .. w*16+15 (two 8-wide passes)
    #pragma unroll
    for (int pass = 0; pass < 2; ++pass) {
        const int h0 = w * 16 + pass * 8;
        float acc[8];
        #pragma unroll
        for (int i = 0; i < 8; ++i) acc[i] = b1[h0 + i];
        #pragma unroll 8
        for (int c = 0; c < 64; ++c) {
            float xv = xs[c][col];
            #pragma unroll
            for (int i = 0; i < 8; ++i)
                acc[i] = fmaf(W1[(h0 + i) * 64 + c], xv, acc[i]);
        }
        #pragma unroll
        for (int i = 0; i < 8; ++i)
            hs[h0 + i][col] = fmaxf(acc[i], 0.f);
    }
    __syncthreads();

    // conv2: 64 outputs, wave w handles o = w*8 .. w*8+7
    {
        const int o0 = w * 8;
        float acc[8];
        #pragma unroll
        for (int i = 0; i < 8; ++i) acc[i] = b2[o0 + i];
        #pragma unroll 8
        for (int c = 0; c < 128; ++c) {
            float hv = hs[c][col];
            #pragma unroll
            for (int i = 0; i < 8; ++i)
                acc[i] = fmaf(W2[(o0 + i) * 128 + c], hv, acc[i]);
        }
        #pragma unroll
        for (int i = 0; i < 8; ++i) {
            const int o = o0 + i;
            float tv = xs[o][col] + fmaxf(acc[i], 0.f);   // fea + relu(conv2)
            tbuf[(size_t)o * N + n0 + col] = tv;
            float s = tv, q = tv * tv;
            #pragma unroll
            for (int m = 1; m < 64; m <<= 1) {
                s += __shfl_xor(s, m);
                q += __shfl_xor(q, m);
            }
            if (col == 0) {
                pb2s[o * nb + bx] = s;
                pb2q[o * nb + bx] = q;
            }
        }
    }
}

// ---------- LN2 finalize + normalize -> out ----------
// grid N/32, 256 thr.
__global__ __launch_bounds__(256)
void ln_finish_k(const float* __restrict__ tbuf, const float* __restrict__ pb2s,
                 const float* __restrict__ pb2q, float* __restrict__ out, int N) {
    __shared__ float redS[4][64], redQ[4][64];
    __shared__ float lnA[64], lnB[64];
    const int tid = threadIdx.x;
    const int nb = N >> 6;
    {
        const int c = tid & 63, part = tid >> 6;     // 4 parts
        const int per = nb >> 2;                     // 20
        float s = 0.f, q = 0.f;
        for (int i = 0; i < per; ++i) {
            int b = part * per + i;
            s += pb2s[c * nb + b];
            q += pb2q[c * nb + b];
        }
        redS[part][c] = s; redQ[part][c] = q;
    }
    __syncthreads();
    if (tid < 64) {
        float s = 0.f, q = 0.f;
        #pragma unroll
        for (int p = 0; p < 4; ++p) { s += redS[p][tid]; q += redQ[p][tid]; }
        float mean = s / (float)N;
        float var = q / (float)N - mean * mean;
        float rstd = rsqrtf(var + EPSV);
        lnA[tid] = rstd;
        lnB[tid] = -mean * rstd;
    }
    __syncthreads();
    const int n0 = blockIdx.x * 32;
    for (int i = tid; i < 64 * 32; i += 256) {
        int c = i >> 5, nn = i & 31;
        out[(size_t)c * N + n0 + nn] = tbuf[(size_t)c * N + n0 + nn] * lnA[c] + lnB[c];
    }
}

extern "C" void kernel_launch(void* const* d_in, const int* in_sizes, int n_in,
                              void* d_out, int out_size, void* d_ws, size_t ws_size,
                              hipStream_t stream) {
    const float* fpix = (const float*)d_in[0];
    const float* fkey = (const float*)d_in[1];
    const float* Wq = (const float*)d_in[2];  const float* bq = (const float*)d_in[3];
    const float* Wk = (const float*)d_in[4];  const float* bk = (const float*)d_in[5];
    const float* Wv = (const float*)d_in[6];  const float* bv = (const float*)d_in[7];
    const float* Wm = (const float*)d_in[8];  const float* bm = (const float*)d_in[9];
    const float* W1 = (const float*)d_in[10]; const float* b1 = (const float*)d_in[11];
    const float* W2 = (const float*)d_in[12]; const float* b2 = (const float*)d_in[13];
    float* outp = (float*)d_out;

    const int N = in_sizes[0] / DMODEL;   // 5120
    const int M = in_sizes[1] / DMODEL;   // 4096

    char* wsb = (char*)d_ws;
    short4v* qfrag = (short4v*)(wsb);                   // 655360
    short4v* kfrag = (short4v*)(wsb + 655360);          // 524288
    short4v* vfrag = (short4v*)(wsb + 1179648);         // 524288
    float*   xatt  = (float*)(wsb + 1703936);           // 1310720
    float*   resid = (float*)(wsb + 3014656);           // 1310720
    float*   tbuf  = (float*)(wsb + 4325376);           // 1310720
    float*   pb1s  = (float*)(wsb + 5636096);           // 20480
    float*   pb1q  = (float*)(wsb + 5656576);           // 20480
    float*   pb2s  = (float*)(wsb + 5677056);           // 20480
    float*   pb2q  = (float*)(wsb + 5697536);           // 20480

    proj_all_k<<<dim3(M / 64 + N / 64), 256, 0, stream>>>(Wk, bk, Wv, bv, Wq, bq,
                                                          fkey, fpix, kfrag, vfrag,
                                                          qfrag, M, N);
    attn_mfma_k<<<dim3(N / 16, NHEADS), 256, 0, stream>>>(qfrag, kfrag, vfrag, xatt, N, M);
    conv_wm_resid_k<<<dim3(N / 64, 4), 256, 0, stream>>>(Wm, bm, xatt, fpix, resid,
                                                         pb1s, pb1q, N);
    mlp_fused_k<<<dim3(N / 64), 512, 0, stream>>>(W1, b1, W2, b2, resid,
                                                  pb1s, pb1q, tbuf, pb2s, pb2q, N);
    ln_finish_k<<<dim3(N / 32), 256, 0, stream>>>(tbuf, pb2s, pb2q, outp, N);
}